// Round 6
// baseline (121.525 us; speedup 1.0000x reference)
//
#include <hip/hip_runtime.h>
#include <cstdint>
#include <cstddef>

#define CIN   256
#define COUT  128

typedef float  f32x4  __attribute__((ext_vector_type(4)));
typedef __bf16 bf16x8 __attribute__((ext_vector_type(8)));

// ---------------- workspace layout (bytes) ----------------
// xf: frag-ordered padded x: [b][row(66)][q(32)][col(66)][8e], e: ci = q*8+e
#define XF_BYTES   (16ull*66*32*66*8*2)         // 35,684,352
#define WF_OFF     XF_BYTES
#define WF_BYTES   (16ull*8*4*128*8*2)          // 1,048,576   bf16 w, frag-ordered
#define SPAD_OFF   (WF_OFF + WF_BYTES)
#define SPAD_BYTES (16ull*66*66*4)              // 278,784     fp32 per-pixel sum(x^2)
#define KSQ_OFF    (SPAD_OFF + SPAD_BYTES)
#define WS_NEEDED  (KSQ_OFF + 512)

__device__ __forceinline__ unsigned short f2bf(float f) {
  unsigned int u = __float_as_uint(f);
  u += 0x7fffu + ((u >> 16) & 1u);              // RNE
  return (unsigned short)(u >> 16);
}

// ---------------- prep: frag-ordered padded x + channel sum of x^2 -------
// block = one padded row (b, row); LDS transpose [col][ci] -> [q][col][8]
__global__ __launch_bounds__(256) void prep_x2(
    const float* __restrict__ x, unsigned short* __restrict__ xf,
    float* __restrict__ spad)
{
  __shared__ __align__(16) unsigned short lw[66*258 + 8];  // stride 258 (bank-spread)
  int blk = blockIdx.x;                          // b*66 + row
  int b = blk / 66, row = blk - b*66;
  int t = threadIdx.x, wave = t >> 6, lane = t & 63;
  bool interior = (row >= 1 && row <= 64);
  int iy = row - 1;

  if (interior) {
    #pragma unroll
    for (int p = 0; p < 16; ++p) {
      int cx = 4*p + wave;                       // input col 0..63
      f32x4 v = *(const f32x4*)(x + (((size_t)b*64 + iy)*64 + cx)*CIN + lane*4);
      ushort4 h; h.x=f2bf(v.x); h.y=f2bf(v.y); h.z=f2bf(v.z); h.w=f2bf(v.w);
      *(ushort4*)&lw[(size_t)(cx+1)*258 + lane*4] = h;
      float s = v.x*v.x + v.y*v.y + v.z*v.z + v.w*v.w;
      #pragma unroll
      for (int off = 32; off > 0; off >>= 1) s += __shfl_down(s, off);
      if (lane == 0) spad[(size_t)blk*66 + cx + 1] = s;
    }
    if (t < 2) spad[(size_t)blk*66 + t*65] = 0.f;
    if (t < 64) {                                // zero pad cols 0 and 65
      int col = (t & 1) * 65, q = t >> 1;
      *(uint4*)&lw[(size_t)col*258 + q*8] = (uint4){0,0,0,0};
    }
  } else {
    if (t < 66) spad[(size_t)blk*66 + t] = 0.f;
  }
  __syncthreads();

  size_t obase = (size_t)blk * 32 * 66 * 8;
  #pragma unroll
  for (int k = 0; k < 9; ++k) {
    int un = k*256 + t;                          // unit = q*66 + col
    if (un < 2112) {
      int q = un / 66, col = un - q*66;
      uint4 val = interior ? *(uint4*)&lw[(size_t)col*258 + q*8]
                           : (uint4){0u,0u,0u,0u};
      *(uint4*)(xf + obase + (size_t)un*8) = val;
    }
  }
}

// ---------------- prep: fragment-ordered weights + k_sq ----------------
// wf element index: (((tap*8 + c8)*4 + q)*128 + co)*8 + e, ci = c8*32 + q*8 + e
__global__ __launch_bounds__(256) void prep_w2(
    const float* __restrict__ w, unsigned short* __restrict__ wf,
    float* __restrict__ ksq)
{
  int blk = blockIdx.x;                          // tap*8 + c8
  int tap = blk >> 3, c8 = blk & 7;
  int t = threadIdx.x;
  #pragma unroll
  for (int rr = 0; rr < 2; ++rr) {
    int row = rr*256 + t;                        // 0..511 = q*128 + co
    int q = row >> 7, co = row & 127;
    float s = 0.f;
    union { unsigned short u[8]; uint4 v; } hh;
    #pragma unroll
    for (int e = 0; e < 8; ++e) {
      int ci = c8*32 + q*8 + e;
      float v = w[((size_t)tap*256 + ci)*COUT + co];
      s += v*v;
      hh.u[e] = f2bf(v);
    }
    *(uint4*)(wf + ((size_t)blk*4 + q)*128*8 + (size_t)co*8) = hh.v;
    atomicAdd(ksq + co, s);
  }
}

// ---------------- main fused kernel ----------------
// grid = 2048 (XCD-swizzled): bid -> b = bid>>7, u = (bid>>1)&63, py = bid&1
// block = 256 (4 waves): wave = (px<<1)|coh, wave tile = 64 v x 64 co
// NO LDS staging, NO barriers in the K-loop: A streams from frag-ordered
// global (L1-resident per chunk), B from L2 with rolling register banks.
__global__ __launch_bounds__(256, 3) void yat_main(
    const unsigned short* __restrict__ xf,
    const unsigned short* __restrict__ wf,
    const float* __restrict__ spad,
    const float* __restrict__ ksq,
    const float* __restrict__ bias,
    const float* __restrict__ alpha,
    float* __restrict__ out)
{
  __shared__ float srow[132];

  int orig = blockIdx.x;
  int bid = (orig & 7) * 256 + (orig >> 3);              // XCD-contiguous
  int py = bid & 1, u = (bid >> 1) & 63, b = bid >> 7;
  int t = threadIdx.x, wave = t >> 6, lane = t & 63;
  int px = wave >> 1, coh = wave & 1;
  int l15 = lane & 15, l4 = lane >> 4;

  if (t < 132) {
    int r = t / 66, c = t - r*66;
    srow[t] = spad[((size_t)b*66 + (u + py) + r)*66 + c];
  }

  // A per-lane base: xf[b][u+py][q=l4][col = px+l15][..]
  const unsigned short* ab =
      xf + ((((size_t)b*66 + (u + py))*32 + l4)*66 + px + l15)*8;
  // B per-lane base (tap folded): wf + [(py*4+px) tap][q=l4][coh half + l15]
  const unsigned short* wb =
      wf + ((size_t)l4*128 + coh*64 + l15)*8 + (size_t)(py*4 + px)*32768;

  f32x4 acc[4][4];
  #pragma unroll
  for (int i = 0; i < 4; ++i)
    #pragma unroll
    for (int j = 0; j < 4; ++j)
      acc[i][j] = (f32x4){0.f, 0.f, 0.f, 0.f};

  bf16x8 B0[2][4], B1[2][4];                     // [bb][nt], a=0 / a=1 banks

  // B frag elem offset: AA*262144 + bb*65536 + c8*4096 + nt*128
#define LOAD_B(BANK, AA, C8)                                               \
  {                                                                        \
    _Pragma("unroll")                                                      \
    for (int bb = 0; bb < 2; ++bb)                                         \
      _Pragma("unroll")                                                    \
      for (int nt = 0; nt < 4; ++nt)                                       \
        BANK[bb][nt] = *(const bf16x8*)(                                   \
            wb + (size_t)(AA)*262144 + (size_t)bb*65536 +                  \
                 (size_t)(C8)*4096 + nt*128);                              \
  }

  // A frag elem offset: AA*16896 (row+1) + C8*2112 (4 q-planes) + (mt*16+bb)*8
#define COMPUTE_HALF(AA, BANK, C8)                                         \
  {                                                                        \
    _Pragma("unroll")                                                      \
    for (int bb = 0; bb < 2; ++bb) {                                       \
      bf16x8 Af[4];                                                        \
      _Pragma("unroll")                                                    \
      for (int mt = 0; mt < 4; ++mt)                                       \
        Af[mt] = *(const bf16x8*)(ab + (size_t)(AA)*16896 +                \
            (size_t)(C8)*2112 + (mt*16 + bb)*8);                           \
      __builtin_amdgcn_s_setprio(1);                                       \
      _Pragma("unroll")                                                    \
      for (int mt = 0; mt < 4; ++mt)                                       \
        _Pragma("unroll")                                                  \
        for (int nt = 0; nt < 4; ++nt)                                     \
          acc[mt][nt] = __builtin_amdgcn_mfma_f32_16x16x32_bf16(           \
              Af[mt], BANK[bb][nt], acc[mt][nt], 0, 0, 0);                 \
      __builtin_amdgcn_s_setprio(0);                                       \
    }                                                                      \
  }

  LOAD_B(B0, 0, 0);
  #pragma unroll
  for (int c8 = 0; c8 < 8; ++c8) {
    LOAD_B(B1, 1, c8);
    __builtin_amdgcn_sched_barrier(0);
    COMPUTE_HALF(0, B0, c8);                     // a=0, B loaded a chunk ago
    if (c8 < 7) LOAD_B(B0, 0, c8 + 1);
    __builtin_amdgcn_sched_barrier(0);
    COMPUTE_HALF(1, B1, c8);                     // a=1, covered by a=0 compute
    __builtin_amdgcn_sched_barrier(0);
  }

#undef LOAD_B
#undef COMPUTE_HALF

  __syncthreads();                               // srow visibility for epilogue

  // ---------------- epilogue ----------------
  float scale = powf(sqrtf(128.f) / log1pf(128.f), alpha[0]);
  int oy = 2*u + py;
  float kq[4], bi[4];
  #pragma unroll
  for (int nt = 0; nt < 4; ++nt) {
    int n = coh*64 + nt*16 + l15;
    kq[nt] = ksq[n]; bi[nt] = bias[n];
  }
  size_t orow = ((size_t)b*128 + oy) * 128 * COUT;
  #pragma unroll
  for (int mt = 0; mt < 4; ++mt) {
    #pragma unroll
    for (int r = 0; r < 4; ++r) {
      int v = mt*16 + l4*4 + r;
      float ps = srow[v+px] + srow[v+px+1] + srow[66 + v+px] + srow[66 + v+px+1];
      #pragma unroll
      for (int nt = 0; nt < 4; ++nt) {
        float dot = acc[mt][nt][r];
        float dist = ps + kq[nt] - 2.f*dot + 1e-5f;
        float y = (dot*dot/dist + bi[nt]) * scale;
        int n = coh*64 + nt*16 + l15;
        out[orow + (size_t)(2*v + px)*COUT + n] = y;
      }
    }
  }
}

// ---------------- fallback (tiny ws): direct fp32 ----------------
__global__ __launch_bounds__(256) void fb_ksq(const float* __restrict__ w,
                                              float* __restrict__ ksq) {
  __shared__ float red[256];
  int co = blockIdx.x, t = threadIdx.x;
  float s = 0.f;
  for (int j = t; j < 4096; j += 256) { float v = w[(size_t)j*COUT + co]; s += v*v; }
  red[t] = s; __syncthreads();
  for (int off = 128; off > 0; off >>= 1) {
    if (t < off) red[t] += red[t + off];
    __syncthreads();
  }
  if (t == 0) ksq[co] = red[0];
}

__global__ __launch_bounds__(256) void fb_main(
    const float* __restrict__ x, const float* __restrict__ w,
    const float* __restrict__ bias, const float* __restrict__ alpha,
    const float* __restrict__ ksq, float* __restrict__ out)
{
  size_t idx = (size_t)blockIdx.x * 256 + threadIdx.x;
  int co = (int)(idx & 127);
  int ox = (int)((idx >> 7) & 127);
  int oy = (int)((idx >> 14) & 127);
  int b  = (int)(idx >> 21);
  int py = oy & 1, px = ox & 1, u = oy >> 1, v = ox >> 1;
  float dot = 0.f, ps = 0.f;
  for (int a = 0; a < 2; ++a) {
    int iy = u + py + a - 1;
    if (iy < 0 || iy > 63) continue;
    for (int b2 = 0; b2 < 2; ++b2) {
      int ix = v + px + b2 - 1;
      if (ix < 0 || ix > 63) continue;
      const float* xp = x + (((size_t)b*64 + iy)*64 + ix)*CIN;
      const float* wp = w + ((size_t)((py + 2*a)*4 + (px + 2*b2))*CIN)*COUT + co;
      for (int ci = 0; ci < CIN; ++ci) {
        float xv = xp[ci];
        dot += xv * wp[(size_t)ci*COUT];
        ps  += xv * xv;
      }
    }
  }
  float dist = ps + ksq[co] - 2.f*dot + 1e-5f;
  float scale = powf(sqrtf(128.f) / log1pf(128.f), alpha[0]);
  out[idx] = (dot*dot/dist + bias[co]) * scale;
}

// ---------------- launcher ----------------
extern "C" void kernel_launch(void* const* d_in, const int* in_sizes, int n_in,
                              void* d_out, int out_size, void* d_ws, size_t ws_size,
                              hipStream_t stream)
{
  const float* x     = (const float*)d_in[0];
  const float* w     = (const float*)d_in[1];
  const float* bias  = (const float*)d_in[2];
  const float* alpha = (const float*)d_in[3];
  float* out = (float*)d_out;

  if (ws_size < WS_NEEDED) {
    float* ksq = (float*)d_ws;
    fb_ksq<<<128, 256, 0, stream>>>(w, ksq);
    fb_main<<<131072, 256, 0, stream>>>(x, w, bias, alpha, ksq, out);
    return;
  }

  unsigned short* xfp = (unsigned short*)d_ws;
  unsigned short* wfp = (unsigned short*)((char*)d_ws + WF_OFF);
  float* spad = (float*)((char*)d_ws + SPAD_OFF);
  float* ksq  = (float*)((char*)d_ws + KSQ_OFF);

  hipMemsetAsync(ksq, 0, 512, stream);
  prep_x2<<<1056, 256, 0, stream>>>(x, xfp, spad);
  prep_w2<<<128, 256, 0, stream>>>(w, wfp, ksq);
  yat_main<<<2048, 256, 0, stream>>>(xfp, wfp, spad, ksq, bias, alpha, out);
}

// Round 7
// 118.613 us; speedup vs baseline: 1.0246x; 1.0246x over previous
//
#include <hip/hip_runtime.h>
#include <cstdint>
#include <cstddef>

#define CIN   256
#define COUT  128

typedef float  f32x4  __attribute__((ext_vector_type(4)));
typedef __bf16 bf16x8 __attribute__((ext_vector_type(8)));

// ---------------- workspace layout (bytes) ----------------
// xf: frag-ordered padded x: [b][row(66)][q(32)][col(66)][8e], e: ci = q*8+e
#define XF_BYTES   (16ull*66*32*66*8*2)         // 35,684,352
#define WF_OFF     XF_BYTES
#define WF_BYTES   (16ull*8*4*128*8*2)          // 1,048,576   bf16 w, frag-ordered
#define SPAD_OFF   (WF_OFF + WF_BYTES)
#define SPAD_BYTES (16ull*66*66*4)              // 278,784     fp32 per-pixel sum(x^2)
#define KSQ_OFF    (SPAD_OFF + SPAD_BYTES)
#define WS_NEEDED  (KSQ_OFF + 512)

__device__ __forceinline__ unsigned short f2bf(float f) {
  unsigned int u = __float_as_uint(f);
  u += 0x7fffu + ((u >> 16) & 1u);              // RNE
  return (unsigned short)(u >> 16);
}

// ---------------- prep: frag-ordered padded x + channel sum of x^2 -------
// block = one padded row (b, row); LDS transpose [col][ci] -> [q][col][8]
__global__ __launch_bounds__(256) void prep_x2(
    const float* __restrict__ x, unsigned short* __restrict__ xf,
    float* __restrict__ spad)
{
  __shared__ __align__(16) unsigned short lw[66*258 + 8];  // stride 258 (bank-spread)
  int blk = blockIdx.x;                          // b*66 + row
  int b = blk / 66, row = blk - b*66;
  int t = threadIdx.x, wave = t >> 6, lane = t & 63;
  bool interior = (row >= 1 && row <= 64);
  int iy = row - 1;

  if (interior) {
    #pragma unroll
    for (int p = 0; p < 16; ++p) {
      int cx = 4*p + wave;                       // input col 0..63
      f32x4 v = *(const f32x4*)(x + (((size_t)b*64 + iy)*64 + cx)*CIN + lane*4);
      ushort4 h; h.x=f2bf(v.x); h.y=f2bf(v.y); h.z=f2bf(v.z); h.w=f2bf(v.w);
      *(ushort4*)&lw[(size_t)(cx+1)*258 + lane*4] = h;
      float s = v.x*v.x + v.y*v.y + v.z*v.z + v.w*v.w;
      #pragma unroll
      for (int off = 32; off > 0; off >>= 1) s += __shfl_down(s, off);
      if (lane == 0) spad[(size_t)blk*66 + cx + 1] = s;
    }
    if (t < 2) spad[(size_t)blk*66 + t*65] = 0.f;
    if (t < 64) {                                // zero pad cols 0 and 65
      int col = (t & 1) * 65, q = t >> 1;
      *(uint4*)&lw[(size_t)col*258 + q*8] = (uint4){0,0,0,0};
    }
  } else {
    if (t < 66) spad[(size_t)blk*66 + t] = 0.f;
  }
  __syncthreads();

  size_t obase = (size_t)blk * 32 * 66 * 8;
  #pragma unroll
  for (int k = 0; k < 9; ++k) {
    int un = k*256 + t;                          // unit = q*66 + col
    if (un < 2112) {
      int q = un / 66, col = un - q*66;
      uint4 val = interior ? *(uint4*)&lw[(size_t)col*258 + q*8]
                           : (uint4){0u,0u,0u,0u};
      *(uint4*)(xf + obase + (size_t)un*8) = val;
    }
  }
}

// ---------------- prep: fragment-ordered weights + k_sq ----------------
// wf element index: (((tap*8 + c8)*4 + q)*128 + co)*8 + e, ci = c8*32 + q*8 + e
__global__ __launch_bounds__(256) void prep_w2(
    const float* __restrict__ w, unsigned short* __restrict__ wf,
    float* __restrict__ ksq)
{
  int blk = blockIdx.x;                          // tap*8 + c8
  int tap = blk >> 3, c8 = blk & 7;
  int t = threadIdx.x;
  #pragma unroll
  for (int rr = 0; rr < 2; ++rr) {
    int row = rr*256 + t;                        // 0..511 = q*128 + co
    int q = row >> 7, co = row & 127;
    float s = 0.f;
    union { unsigned short u[8]; uint4 v; } hh;
    #pragma unroll
    for (int e = 0; e < 8; ++e) {
      int ci = c8*32 + q*8 + e;
      float v = w[((size_t)tap*256 + ci)*COUT + co];
      s += v*v;
      hh.u[e] = f2bf(v);
    }
    *(uint4*)(wf + ((size_t)blk*4 + q)*128*8 + (size_t)co*8) = hh.v;
    atomicAdd(ksq + co, s);
  }
}

// ---------------- main fused kernel ----------------
// grid = 2048 (XCD-swizzled): bid -> b = bid>>7, u = (bid>>1)&63, py = bid&1
// block = 256 (4 waves): wave = (px<<1)|coh, wave tile = 64 v x 64 co
// Half-chunk software pipeline with FIFO discipline: loads for half h+1 are
// issued at the TOP of half h (strictly newer than the loads half h consumes),
// so the compiler's dataflow vmcnt waits leave the prefetch in flight.
// No LDS staging, no barriers in the K-loop.
__global__ __launch_bounds__(256, 2) void yat_main(
    const unsigned short* __restrict__ xf,
    const unsigned short* __restrict__ wf,
    const float* __restrict__ spad,
    const float* __restrict__ ksq,
    const float* __restrict__ bias,
    const float* __restrict__ alpha,
    float* __restrict__ out)
{
  __shared__ float srow[132];

  int orig = blockIdx.x;
  int bid = (orig & 7) * 256 + (orig >> 3);              // XCD-contiguous
  int py = bid & 1, u = (bid >> 1) & 63, b = bid >> 7;
  int t = threadIdx.x, wave = t >> 6, lane = t & 63;
  int px = wave >> 1, coh = wave & 1;
  int l15 = lane & 15, l4 = lane >> 4;

  if (t < 132) {
    int r = t / 66, c = t - r*66;
    srow[t] = spad[((size_t)b*66 + (u + py) + r)*66 + c];
  }

  // A per-lane base: xf[b][u+py][q=l4 (+4/c8)][col = px+l15][..]
  const unsigned short* ab =
      xf + ((((size_t)b*66 + (u + py))*32 + l4)*66 + px + l15)*8;
  // B per-lane base (tap folded): wf + [(py*4+px) tap][q=l4][coh half + l15]
  const unsigned short* wb =
      wf + ((size_t)l4*128 + coh*64 + l15)*8 + (size_t)(py*4 + px)*32768;

  f32x4 acc[4][4];
  #pragma unroll
  for (int i = 0; i < 4; ++i)
    #pragma unroll
    for (int j = 0; j < 4; ++j)
      acc[i][j] = (f32x4){0.f, 0.f, 0.f, 0.f};

  bf16x8 Aq[2][2][4];                            // [a-parity][bb][mt]
  bf16x8 Bq[2][2][4];                            // [a-parity][bb][nt]

  // A frag elem offset: AA*16896 (row) + C8*2112 (4 q-planes) + (mt*16+bb)*8
  // B frag elem offset: AA*262144 + bb*65536 + C8*4096 + nt*128
#define ISSUE(P, AA, C8)                                                   \
  {                                                                        \
    _Pragma("unroll")                                                      \
    for (int bb = 0; bb < 2; ++bb)                                         \
      _Pragma("unroll")                                                    \
      for (int mt = 0; mt < 4; ++mt)                                       \
        Aq[P][bb][mt] = *(const bf16x8*)(ab + (size_t)(AA)*16896 +         \
            (size_t)(C8)*2112 + (mt*16 + bb)*8);                           \
    _Pragma("unroll")                                                      \
    for (int bb = 0; bb < 2; ++bb)                                         \
      _Pragma("unroll")                                                    \
      for (int nt = 0; nt < 4; ++nt)                                       \
        Bq[P][bb][nt] = *(const bf16x8*)(wb + (size_t)(AA)*262144 +        \
            (size_t)bb*65536 + (size_t)(C8)*4096 + nt*128);                \
  }

#define MFMA32(P)                                                          \
  {                                                                        \
    __builtin_amdgcn_s_setprio(1);                                         \
    _Pragma("unroll")                                                      \
    for (int bb = 0; bb < 2; ++bb)                                         \
      _Pragma("unroll")                                                    \
      for (int mt = 0; mt < 4; ++mt)                                       \
        _Pragma("unroll")                                                  \
        for (int nt = 0; nt < 4; ++nt)                                     \
          acc[mt][nt] = __builtin_amdgcn_mfma_f32_16x16x32_bf16(           \
              Aq[P][bb][mt], Bq[P][bb][nt], acc[mt][nt], 0, 0, 0);         \
    __builtin_amdgcn_s_setprio(0);                                         \
  }

  // prologue: parity-0 loads for chunk 0 (a=0)
  ISSUE(0, 0, 0);
  __builtin_amdgcn_sched_barrier(0);

  #pragma unroll
  for (int c8 = 0; c8 < 8; ++c8) {
    // HALF a=0: issue parity-1 (A1,B1 of this chunk), consume parity-0
    ISSUE(1, 1, c8);
    __builtin_amdgcn_sched_barrier(0);
    MFMA32(0);
    __builtin_amdgcn_sched_barrier(0);
    // HALF a=1: issue parity-0 for next chunk, consume parity-1
    if (c8 < 7) ISSUE(0, 0, c8 + 1);
    __builtin_amdgcn_sched_barrier(0);
    MFMA32(1);
    __builtin_amdgcn_sched_barrier(0);
  }

#undef ISSUE
#undef MFMA32

  __syncthreads();                               // srow visibility for epilogue

  // ---------------- epilogue ----------------
  float scale = powf(sqrtf(128.f) / log1pf(128.f), alpha[0]);
  int oy = 2*u + py;
  float kq[4], bi[4];
  #pragma unroll
  for (int nt = 0; nt < 4; ++nt) {
    int n = coh*64 + nt*16 + l15;
    kq[nt] = ksq[n]; bi[nt] = bias[n];
  }
  size_t orow = ((size_t)b*128 + oy) * 128 * COUT;
  #pragma unroll
  for (int mt = 0; mt < 4; ++mt) {
    #pragma unroll
    for (int r = 0; r < 4; ++r) {
      int v = mt*16 + l4*4 + r;
      float ps = srow[v+px] + srow[v+px+1] + srow[66 + v+px] + srow[66 + v+px+1];
      #pragma unroll
      for (int nt = 0; nt < 4; ++nt) {
        float dot = acc[mt][nt][r];
        float dist = ps + kq[nt] - 2.f*dot + 1e-5f;
        float y = (dot*dot/dist + bi[nt]) * scale;
        int n = coh*64 + nt*16 + l15;
        out[orow + (size_t)(2*v + px)*COUT + n] = y;
      }
    }
  }
}

// ---------------- fallback (tiny ws): direct fp32 ----------------
__global__ __launch_bounds__(256) void fb_ksq(const float* __restrict__ w,
                                              float* __restrict__ ksq) {
  __shared__ float red[256];
  int co = blockIdx.x, t = threadIdx.x;
  float s = 0.f;
  for (int j = t; j < 4096; j += 256) { float v = w[(size_t)j*COUT + co]; s += v*v; }
  red[t] = s; __syncthreads();
  for (int off = 128; off > 0; off >>= 1) {
    if (t < off) red[t] += red[t + off];
    __syncthreads();
  }
  if (t == 0) ksq[co] = red[0];
}

__global__ __launch_bounds__(256) void fb_main(
    const float* __restrict__ x, const float* __restrict__ w,
    const float* __restrict__ bias, const float* __restrict__ alpha,
    const float* __restrict__ ksq, float* __restrict__ out)
{
  size_t idx = (size_t)blockIdx.x * 256 + threadIdx.x;
  int co = (int)(idx & 127);
  int ox = (int)((idx >> 7) & 127);
  int oy = (int)((idx >> 14) & 127);
  int b  = (int)(idx >> 21);
  int py = oy & 1, px = ox & 1, u = oy >> 1, v = ox >> 1;
  float dot = 0.f, ps = 0.f;
  for (int a = 0; a < 2; ++a) {
    int iy = u + py + a - 1;
    if (iy < 0 || iy > 63) continue;
    for (int b2 = 0; b2 < 2; ++b2) {
      int ix = v + px + b2 - 1;
      if (ix < 0 || ix > 63) continue;
      const float* xp = x + (((size_t)b*64 + iy)*64 + ix)*CIN;
      const float* wp = w + ((size_t)((py + 2*a)*4 + (px + 2*b2))*CIN)*COUT + co;
      for (int ci = 0; ci < CIN; ++ci) {
        float xv = xp[ci];
        dot += xv * wp[(size_t)ci*COUT];
        ps  += xv * xv;
      }
    }
  }
  float dist = ps + ksq[co] - 2.f*dot + 1e-5f;
  float scale = powf(sqrtf(128.f) / log1pf(128.f), alpha[0]);
  out[idx] = (dot*dot/dist + bias[co]) * scale;
}

// ---------------- launcher ----------------
extern "C" void kernel_launch(void* const* d_in, const int* in_sizes, int n_in,
                              void* d_out, int out_size, void* d_ws, size_t ws_size,
                              hipStream_t stream)
{
  const float* x     = (const float*)d_in[0];
  const float* w     = (const float*)d_in[1];
  const float* bias  = (const float*)d_in[2];
  const float* alpha = (const float*)d_in[3];
  float* out = (float*)d_out;

  if (ws_size < WS_NEEDED) {
    float* ksq = (float*)d_ws;
    fb_ksq<<<128, 256, 0, stream>>>(w, ksq);
    fb_main<<<131072, 256, 0, stream>>>(x, w, bias, alpha, ksq, out);
    return;
  }

  unsigned short* xfp = (unsigned short*)d_ws;
  unsigned short* wfp = (unsigned short*)((char*)d_ws + WF_OFF);
  float* spad = (float*)((char*)d_ws + SPAD_OFF);
  float* ksq  = (float*)((char*)d_ws + KSQ_OFF);

  hipMemsetAsync(ksq, 0, 512, stream);
  prep_x2<<<1056, 256, 0, stream>>>(x, xfp, spad);
  prep_w2<<<128, 256, 0, stream>>>(w, wfp, ksq);
  yat_main<<<2048, 256, 0, stream>>>(xfp, wfp, spad, ksq, bias, alpha, out);
}

// Round 8
// 118.006 us; speedup vs baseline: 1.0298x; 1.0051x over previous
//
#include <hip/hip_runtime.h>
#include <cstdint>
#include <cstddef>

#define CIN   256
#define COUT  128

typedef float  f32x4  __attribute__((ext_vector_type(4)));
typedef __bf16 bf16x8 __attribute__((ext_vector_type(8)));
typedef unsigned int u32x4 __attribute__((ext_vector_type(4)));

// ---------------- workspace layout (bytes) ----------------
// xf: frag-ordered padded x: [b][row(66)][q(32)][col(66)][8e], e: ci = q*8+e
#define XF_BYTES   (16ull*66*32*66*8*2)         // 35,684,352
#define WF_OFF     XF_BYTES
#define WF_BYTES   (16ull*8*4*128*8*2)          // 1,048,576   bf16 w, frag-ordered
#define SPAD_OFF   (WF_OFF + WF_BYTES)
#define SPAD_BYTES (16ull*66*66*4)              // 278,784     fp32 per-pixel sum(x^2)
#define KSQ_OFF    (SPAD_OFF + SPAD_BYTES)
#define WS_NEEDED  (KSQ_OFF + 512)

__device__ __forceinline__ unsigned short f2bf(float f) {
  unsigned int u = __float_as_uint(f);
  u += 0x7fffu + ((u >> 16) & 1u);              // RNE
  return (unsigned short)(u >> 16);
}

// ---------------- prep: frag-ordered padded x + channel sum of x^2 -------
// block = one padded row (b, row); LDS transpose [col][ci] -> [q][col][8]
__global__ __launch_bounds__(256) void prep_x2(
    const float* __restrict__ x, unsigned short* __restrict__ xf,
    float* __restrict__ spad)
{
  __shared__ __align__(16) unsigned short lw[66*258 + 8];  // stride 258 (bank-spread)
  int blk = blockIdx.x;                          // b*66 + row
  int b = blk / 66, row = blk - b*66;
  int t = threadIdx.x, wave = t >> 6, lane = t & 63;
  bool interior = (row >= 1 && row <= 64);
  int iy = row - 1;

  if (interior) {
    #pragma unroll
    for (int p = 0; p < 16; ++p) {
      int cx = 4*p + wave;                       // input col 0..63
      f32x4 v = *(const f32x4*)(x + (((size_t)b*64 + iy)*64 + cx)*CIN + lane*4);
      ushort4 h; h.x=f2bf(v.x); h.y=f2bf(v.y); h.z=f2bf(v.z); h.w=f2bf(v.w);
      *(ushort4*)&lw[(size_t)(cx+1)*258 + lane*4] = h;
      float s = v.x*v.x + v.y*v.y + v.z*v.z + v.w*v.w;
      #pragma unroll
      for (int off = 32; off > 0; off >>= 1) s += __shfl_down(s, off);
      if (lane == 0) spad[(size_t)blk*66 + cx + 1] = s;
    }
    if (t < 2) spad[(size_t)blk*66 + t*65] = 0.f;
    if (t < 64) {                                // zero pad cols 0 and 65
      int col = (t & 1) * 65, q = t >> 1;
      *(uint4*)&lw[(size_t)col*258 + q*8] = (uint4){0,0,0,0};
    }
  } else {
    if (t < 66) spad[(size_t)blk*66 + t] = 0.f;
  }
  __syncthreads();

  size_t obase = (size_t)blk * 32 * 66 * 8;
  #pragma unroll
  for (int k = 0; k < 9; ++k) {
    int un = k*256 + t;                          // unit = q*66 + col
    if (un < 2112) {
      int q = un / 66, col = un - q*66;
      uint4 val = interior ? *(uint4*)&lw[(size_t)col*258 + q*8]
                           : (uint4){0u,0u,0u,0u};
      *(uint4*)(xf + obase + (size_t)un*8) = val;
    }
  }
}

// ---------------- prep: fragment-ordered weights + k_sq ----------------
// wf element index: (((tap*8 + c8)*4 + q)*128 + co)*8 + e, ci = c8*32 + q*8 + e
__global__ __launch_bounds__(256) void prep_w2(
    const float* __restrict__ w, unsigned short* __restrict__ wf,
    float* __restrict__ ksq)
{
  int blk = blockIdx.x;                          // tap*8 + c8
  int tap = blk >> 3, c8 = blk & 7;
  int t = threadIdx.x;
  #pragma unroll
  for (int rr = 0; rr < 2; ++rr) {
    int row = rr*256 + t;                        // 0..511 = q*128 + co
    int q = row >> 7, co = row & 127;
    float s = 0.f;
    union { unsigned short u[8]; uint4 v; } hh;
    #pragma unroll
    for (int e = 0; e < 8; ++e) {
      int ci = c8*32 + q*8 + e;
      float v = w[((size_t)tap*256 + ci)*COUT + co];
      s += v*v;
      hh.u[e] = f2bf(v);
    }
    *(uint4*)(wf + ((size_t)blk*4 + q)*128*8 + (size_t)co*8) = hh.v;
    atomicAdd(ksq + co, s);
  }
}

// ---------------- main fused kernel ----------------
// grid = 2048 (XCD-swizzled): bid -> b = bid>>7, u = (bid>>1)&63, py = bid&1
// block = 256 (4 waves): wave = (px<<1)|coh, wave tile = 64 v x 64 co
// Inline-asm software pipeline: 16 asm global_load_dwordx4 per half-chunk
// into named register banks; manual s_waitcnt vmcnt(16) (+sched_barrier,
// rule #18) before each 32-MFMA cluster. Compiler never drains the queue.
__global__ __launch_bounds__(256, 2) void yat_main(
    const unsigned short* __restrict__ xf,
    const unsigned short* __restrict__ wf,
    const float* __restrict__ spad,
    const float* __restrict__ ksq,
    const float* __restrict__ bias,
    const float* __restrict__ alpha,
    float* __restrict__ out)
{
  __shared__ float srow[132];

  int orig = blockIdx.x;
  int bid = (orig & 7) * 256 + (orig >> 3);              // XCD-contiguous
  int py = bid & 1, u = (bid >> 1) & 63, b = bid >> 7;
  int t = threadIdx.x, wave = t >> 6, lane = t & 63;
  int px = wave >> 1, coh = wave & 1;
  int l15 = lane & 15, l4 = lane >> 4;

  if (t < 132) {
    int r = t / 66, c = t - r*66;
    srow[t] = spad[((size_t)b*66 + (u + py) + r)*66 + c];
  }

  // A per-lane base: xf[b][u+py][q=l4 (+4/c8)][col = px+l15][..]
  const unsigned short* ab =
      xf + ((((size_t)b*66 + (u + py))*32 + l4)*66 + px + l15)*8;
  // B per-lane base (tap folded): wf + [(py*4+px) tap][q=l4][coh half + l15]
  const unsigned short* wb =
      wf + ((size_t)l4*128 + coh*64 + l15)*8 + (size_t)(py*4 + px)*32768;

  f32x4 acc[4][4];
  #pragma unroll
  for (int i = 0; i < 4; ++i)
    #pragma unroll
    for (int j = 0; j < 4; ++j)
      acc[i][j] = (f32x4){0.f, 0.f, 0.f, 0.f};

  u32x4 Aq0[2][4], Bq0[2][4], Aq1[2][4], Bq1[2][4];      // [bb][mt/nt]

#define GL(dst, base, off)                                                 \
  asm volatile("global_load_dwordx4 %0, %1, off offset:%c2"                \
               : "=v"(dst) : "v"(base), "i"(off))

  // byte offsets: A: AA*33792 + C8*4224 + (mt*256 + bb*16)
  //               B: AA*524288 + bb*131072 + C8*8192 + nt*256
#define ISSUE(SUF, AA, C8)                                                 \
  {                                                                        \
    const char* pa  = (const char*)ab + (AA)*33792 + (C8)*4224;            \
    const char* pb0 = (const char*)wb + (AA)*524288 + (C8)*8192;           \
    const char* pb1 = pb0 + 131072;                                        \
    GL(Aq##SUF[0][0], pa, 0);   GL(Aq##SUF[0][1], pa, 256);                \
    GL(Aq##SUF[0][2], pa, 512); GL(Aq##SUF[0][3], pa, 768);                \
    GL(Aq##SUF[1][0], pa, 16);  GL(Aq##SUF[1][1], pa, 272);                \
    GL(Aq##SUF[1][2], pa, 528); GL(Aq##SUF[1][3], pa, 784);                \
    GL(Bq##SUF[0][0], pb0, 0);   GL(Bq##SUF[0][1], pb0, 256);              \
    GL(Bq##SUF[0][2], pb0, 512); GL(Bq##SUF[0][3], pb0, 768);              \
    GL(Bq##SUF[1][0], pb1, 0);   GL(Bq##SUF[1][1], pb1, 256);              \
    GL(Bq##SUF[1][2], pb1, 512); GL(Bq##SUF[1][3], pb1, 768);              \
  }

#define MFMA32(SUF)                                                        \
  {                                                                        \
    __builtin_amdgcn_s_setprio(1);                                         \
    _Pragma("unroll")                                                      \
    for (int bb = 0; bb < 2; ++bb)                                         \
      _Pragma("unroll")                                                    \
      for (int mt = 0; mt < 4; ++mt)                                       \
        _Pragma("unroll")                                                  \
        for (int nt = 0; nt < 4; ++nt)                                     \
          acc[mt][nt] = __builtin_amdgcn_mfma_f32_16x16x32_bf16(           \
              __builtin_bit_cast(bf16x8, Aq##SUF[bb][mt]),                 \
              __builtin_bit_cast(bf16x8, Bq##SUF[bb][nt]),                 \
              acc[mt][nt], 0, 0, 0);                                       \
    __builtin_amdgcn_s_setprio(0);                                         \
  }

#define SB __builtin_amdgcn_sched_barrier(0)
#define VMW(N) do { asm volatile("s_waitcnt vmcnt(" #N ")" ::: "memory");  \
                    SB; } while (0)

  // prologue: parity-0 loads for chunk 0 (a=0)
  ISSUE(0, 0, 0); SB;

  #pragma unroll
  for (int c8 = 0; c8 < 8; ++c8) {
    // HALF a=0: issue parity-1 of this chunk, consume parity-0
    ISSUE(1, 1, c8); SB;
    VMW(16);                                    // p0 retired; p1 in flight
    MFMA32(0); SB;
    // HALF a=1: issue parity-0 of next chunk, consume parity-1
    if (c8 < 7) { ISSUE(0, 0, c8 + 1); SB; VMW(16); }
    else        { VMW(0); }
    MFMA32(1); SB;
  }

#undef GL
#undef ISSUE
#undef MFMA32
#undef VMW
#undef SB

  __syncthreads();                               // srow visibility for epilogue

  // ---------------- epilogue ----------------
  float scale = powf(sqrtf(128.f) / log1pf(128.f), alpha[0]);
  int oy = 2*u + py;
  float kq[4], bi[4];
  #pragma unroll
  for (int nt = 0; nt < 4; ++nt) {
    int n = coh*64 + nt*16 + l15;
    kq[nt] = ksq[n]; bi[nt] = bias[n];
  }
  size_t orow = ((size_t)b*128 + oy) * 128 * COUT;
  #pragma unroll
  for (int mt = 0; mt < 4; ++mt) {
    #pragma unroll
    for (int r = 0; r < 4; ++r) {
      int v = mt*16 + l4*4 + r;
      float ps = srow[v+px] + srow[v+px+1] + srow[66 + v+px] + srow[66 + v+px+1];
      #pragma unroll
      for (int nt = 0; nt < 4; ++nt) {
        float dot = acc[mt][nt][r];
        float dist = ps + kq[nt] - 2.f*dot + 1e-5f;
        float y = (dot*dot/dist + bi[nt]) * scale;
        int n = coh*64 + nt*16 + l15;
        out[orow + (size_t)(2*v + px)*COUT + n] = y;
      }
    }
  }
}

// ---------------- fallback (tiny ws): direct fp32 ----------------
__global__ __launch_bounds__(256) void fb_ksq(const float* __restrict__ w,
                                              float* __restrict__ ksq) {
  __shared__ float red[256];
  int co = blockIdx.x, t = threadIdx.x;
  float s = 0.f;
  for (int j = t; j < 4096; j += 256) { float v = w[(size_t)j*COUT + co]; s += v*v; }
  red[t] = s; __syncthreads();
  for (int off = 128; off > 0; off >>= 1) {
    if (t < off) red[t] += red[t + off];
    __syncthreads();
  }
  if (t == 0) ksq[co] = red[0];
}

__global__ __launch_bounds__(256) void fb_main(
    const float* __restrict__ x, const float* __restrict__ w,
    const float* __restrict__ bias, const float* __restrict__ alpha,
    const float* __restrict__ ksq, float* __restrict__ out)
{
  size_t idx = (size_t)blockIdx.x * 256 + threadIdx.x;
  int co = (int)(idx & 127);
  int ox = (int)((idx >> 7) & 127);
  int oy = (int)((idx >> 14) & 127);
  int b  = (int)(idx >> 21);
  int py = oy & 1, px = ox & 1, u = oy >> 1, v = ox >> 1;
  float dot = 0.f, ps = 0.f;
  for (int a = 0; a < 2; ++a) {
    int iy = u + py + a - 1;
    if (iy < 0 || iy > 63) continue;
    for (int b2 = 0; b2 < 2; ++b2) {
      int ix = v + px + b2 - 1;
      if (ix < 0 || ix > 63) continue;
      const float* xp = x + (((size_t)b*64 + iy)*64 + ix)*CIN;
      const float* wp = w + ((size_t)((py + 2*a)*4 + (px + 2*b2))*CIN)*COUT + co;
      for (int ci = 0; ci < CIN; ++ci) {
        float xv = xp[ci];
        dot += xv * wp[(size_t)ci*COUT];
        ps  += xv * xv;
      }
    }
  }
  float dist = ps + ksq[co] - 2.f*dot + 1e-5f;
  float scale = powf(sqrtf(128.f) / log1pf(128.f), alpha[0]);
  out[idx] = (dot*dot/dist + bias[co]) * scale;
}

// ---------------- launcher ----------------
extern "C" void kernel_launch(void* const* d_in, const int* in_sizes, int n_in,
                              void* d_out, int out_size, void* d_ws, size_t ws_size,
                              hipStream_t stream)
{
  const float* x     = (const float*)d_in[0];
  const float* w     = (const float*)d_in[1];
  const float* bias  = (const float*)d_in[2];
  const float* alpha = (const float*)d_in[3];
  float* out = (float*)d_out;

  if (ws_size < WS_NEEDED) {
    float* ksq = (float*)d_ws;
    fb_ksq<<<128, 256, 0, stream>>>(w, ksq);
    fb_main<<<131072, 256, 0, stream>>>(x, w, bias, alpha, ksq, out);
    return;
  }

  unsigned short* xfp = (unsigned short*)d_ws;
  unsigned short* wfp = (unsigned short*)((char*)d_ws + WF_OFF);
  float* spad = (float*)((char*)d_ws + SPAD_OFF);
  float* ksq  = (float*)((char*)d_ws + KSQ_OFF);

  hipMemsetAsync(ksq, 0, 512, stream);
  prep_x2<<<1056, 256, 0, stream>>>(x, xfp, spad);
  prep_w2<<<128, 256, 0, stream>>>(w, wfp, ksq);
  yat_main<<<2048, 256, 0, stream>>>(xfp, wfp, spad, ksq, bias, alpha, out);
}

// Round 10
// 113.827 us; speedup vs baseline: 1.0676x; 1.0367x over previous
//
#include <hip/hip_runtime.h>
#include <cstdint>
#include <cstddef>

#define CIN   256
#define COUT  128

typedef float  f32x4  __attribute__((ext_vector_type(4)));
typedef __bf16 bf16x8 __attribute__((ext_vector_type(8)));
typedef unsigned int u32x4 __attribute__((ext_vector_type(4)));

// ---------------- workspace layout (bytes) ----------------
// xpad: pixel-major padded x: [b][row 66][col 66][ci 256] bf16
#define XPAD_BYTES (16ull*66*66*256*2)          // 35,684,352
#define WF_OFF     XPAD_BYTES
#define WF_BYTES   (16ull*8*4*128*8*2)          // 1,048,576  bf16 w, frag-ordered
#define SPAD_OFF   (WF_OFF + WF_BYTES)
#define SPAD_BYTES (16ull*66*66*4)              // 278,784    fp32 per-pixel sum(x^2)
#define KSQ_OFF    (SPAD_OFF + SPAD_BYTES)
#define WS_NEEDED  (KSQ_OFF + 512)

__device__ __forceinline__ unsigned short f2bf(float f) {
  unsigned int u = __float_as_uint(f);
  u += 0x7fffu + ((u >> 16) & 1u);              // RNE
  return (unsigned short)(u >> 16);
}

__device__ __forceinline__ void async16(const void* lds, const void* g) {
  __builtin_amdgcn_global_load_lds(
      (const __attribute__((address_space(1))) unsigned int*)g,
      (__attribute__((address_space(3))) unsigned int*)lds, 16, 0, 0);
}

// ---------------- prep: pad+convert x, channel sum of x^2 ----------------
__global__ __launch_bounds__(256) void prep_x(
    const float* __restrict__ x, unsigned short* __restrict__ xpad,
    float* __restrict__ spad)
{
  int wave = threadIdx.x >> 6, lane = threadIdx.x & 63;
  int p = blockIdx.x * 4 + wave;                 // 0..69695 over [16][66][66]
  int b = p / 4356;
  int rem = p - b * 4356;
  int iyp = rem / 66, ixp = rem - iyp * 66;
  bool interior = (iyp >= 1 && iyp <= 64 && ixp >= 1 && ixp <= 64);
  f32x4 v = {0.f, 0.f, 0.f, 0.f};
  if (interior) {
    const float* src = x + (((size_t)b*64 + (iyp-1))*64 + (ixp-1))*CIN + lane*4;
    v = *(const f32x4*)src;
  }
  ushort4 h;
  h.x = f2bf(v.x); h.y = f2bf(v.y); h.z = f2bf(v.z); h.w = f2bf(v.w);
  *(ushort4*)(xpad + (size_t)p*CIN + lane*4) = h;
  float s = v.x*v.x + v.y*v.y + v.z*v.z + v.w*v.w;
  #pragma unroll
  for (int off = 32; off > 0; off >>= 1) s += __shfl_down(s, off);
  if (lane == 0) spad[p] = s;
}

// ---------------- prep: fragment-ordered weights ----------------
// wf element index: (((tap*8 + c8)*4 + q)*128 + co)*8 + e, ci = c8*32 + q*8 + e
__global__ __launch_bounds__(256) void prep_w2(
    const float* __restrict__ w, unsigned short* __restrict__ wf)
{
  int blk = blockIdx.x;                          // tap*8 + c8
  int tap = blk >> 3, c8 = blk & 7;
  int t = threadIdx.x;
  #pragma unroll
  for (int rr = 0; rr < 2; ++rr) {
    int row = rr*256 + t;                        // 0..511 = q*128 + co
    int q = row >> 7, co = row & 127;
    union { unsigned short u[8]; uint4 v; } hh;
    #pragma unroll
    for (int e = 0; e < 8; ++e) {
      int ci = c8*32 + q*8 + e;
      hh.u[e] = f2bf(w[((size_t)tap*256 + ci)*COUT + co]);
    }
    *(uint4*)(wf + ((size_t)blk*4 + q)*128*8 + (size_t)co*8) = hh.v;
  }
}

// ---------------- ksq: per-cout kernel squared norm ----------------
__global__ __launch_bounds__(256) void fb_ksq(const float* __restrict__ w,
                                              float* __restrict__ ksq) {
  __shared__ float red[256];
  int co = blockIdx.x, t = threadIdx.x;
  float s = 0.f;
  for (int j = t; j < 4096; j += 256) { float v = w[(size_t)j*COUT + co]; s += v*v; }
  red[t] = s; __syncthreads();
  for (int off = 128; off > 0; off >>= 1) {
    if (t < off) red[t] += red[t + off];
    __syncthreads();
  }
  if (t == 0) ksq[co] = red[0];
}

// ---------------- main fused kernel ----------------
// grid = 2048 (XCD-swizzled): bid -> b = bid>>7, u = (bid>>1)&63, py = bid&1
// block = 256 (4 waves): wave = (px<<1)|coh, wave tile = 64 v x 64 co
// A: depth-3 LDS staging (global_load_lds), consumed via asm ds_read_b128.
// B: depth-2 register banks via asm global_load_dwordx4.
// All waits manual, per-site counted vmcnt/lgkmcnt; raw s_barrier; sched_barrier
// lattice keeps compiler loads out of the counted region.
__global__ __launch_bounds__(256, 2) void yat_main(
    const unsigned short* __restrict__ xpad,
    const unsigned short* __restrict__ wf,
    const float* __restrict__ spad,
    const float* __restrict__ ksq,
    const float* __restrict__ bias,
    const float* __restrict__ alpha,
    float* __restrict__ out)
{
  __shared__ __align__(16) unsigned short xs[3][4224];   // 3 x 8448 B
  __shared__ float srow[132];

  int orig = blockIdx.x;
  int bid = (orig & 7) * 256 + (orig >> 3);              // XCD-contiguous
  int py = bid & 1, u = (bid >> 1) & 63, b = bid >> 7;
  int t = threadIdx.x, wave = t >> 6, lane = t & 63;
  int px = wave >> 1, coh = wave & 1;
  int l15 = lane & 15, l4 = lane >> 4;

  if (t < 132) {
    int r = t / 66, c = t - r*66;
    srow[t] = spad[((size_t)b*66 + (u + py) + r)*66 + c];
  }

  const size_t xrow = ((size_t)b*66 + (u + py)) * 66 * CIN;

  // staging source offsets (shorts), chunk-invariant part; segs: (a*4+q)*66+col
  size_t soff0, soff1, tailoff;
  {
    int s = t;                                   // seg t
    int a = s / 264; int r2 = s - a*264;
    int q = r2 / 66; int c = r2 - q*66;
    soff0 = xrow + (size_t)(a*66 + c)*CIN + q*8;
    s = 256 + t;                                 // seg 256+t
    a = s / 264; r2 = s - a*264;
    q = r2 / 66; c = r2 - q*66;
    soff1 = xrow + (size_t)(a*66 + c)*CIN + q*8;
    int s2 = 248 + (t & 15);                     // tail segs 512..527 (uniform!)
    int q2 = s2 / 66, c2 = s2 - q2*66;
    tailoff = xrow + (size_t)(66 + c2)*CIN + q2*8;
  }

  // LDS byte address of this lane's A-frag base (low 32 bits of generic)
  unsigned ab_lds = (unsigned)(unsigned long long)(&xs[0][0])
                    + (unsigned)((l4*66 + l15 + px) * 16);
  // B per-lane base (tap folded): wf + [q=l4][coh half + l15] + (py,px) tap
  const unsigned short* wb =
      wf + ((size_t)l4*128 + coh*64 + l15)*8 + (size_t)(py*4 + px)*32768;

  f32x4 acc[4][4];
  #pragma unroll
  for (int i = 0; i < 4; ++i)
    #pragma unroll
    for (int j = 0; j < 4; ++j)
      acc[i][j] = (f32x4){0.f, 0.f, 0.f, 0.f};

  u32x4 B0[2][4], B1[2][4];                      // B banks (even/odd half)
  u32x4 Af[2][4];                                // A frags of current half
  u32x4 tvA, tvB;                                // staged tail values

#define SB  __builtin_amdgcn_sched_barrier(0)
#define BAR __builtin_amdgcn_s_barrier()
#define VMW(N) do { asm volatile("s_waitcnt vmcnt(" #N ")" ::: "memory"); SB; } while (0)
#define LGK(N) do { asm volatile("s_waitcnt lgkmcnt(" #N ")" ::: "memory"); SB; } while (0)

#define GLB(dst, base, off)                                                \
  asm volatile("global_load_dwordx4 %0, %1, off offset:%c2"                \
               : "=v"(dst) : "v"(base), "i"(off))

#define DSR(dst, off)                                                      \
  asm volatile("ds_read_b128 %0, %1 offset:%c2"                            \
               : "=v"(dst) : "v"(ab_lds), "i"(off))

  // stage chunk K into LDS buffer BUF; tail 16B -> TV register (uniform load)
#define STAGE(BUF, K, TV)                                                  \
  {                                                                        \
    async16(&xs[BUF][(size_t)(0*256 + wave*64)*8], xpad + soff0 + (K)*32); \
    async16(&xs[BUF][(size_t)(1*256 + wave*64)*8], xpad + soff1 + (K)*32); \
    SB;                                                                    \
    GLB(TV, (const char*)(xpad + tailoff + (K)*32), 0);                    \
    SB;                                                                    \
  }

#define TAILW(BUF, TV)                                                     \
  { if (t < 16) *((u32x4*)&xs[BUF][(size_t)(512 + t)*8]) = TV; }

  // B frag byte offsets from wb: AA*524288 + bb*131072 + C8*8192 + nt*256
#define ISSUEB(BANK, AA, C8)                                               \
  {                                                                        \
    const char* pb0 = (const char*)wb + (AA)*524288 + (C8)*8192;           \
    const char* pb1 = pb0 + 131072;                                        \
    GLB(BANK[0][0], pb0, 0);   GLB(BANK[0][1], pb0, 256);                  \
    GLB(BANK[0][2], pb0, 512); GLB(BANK[0][3], pb0, 768);                  \
    GLB(BANK[1][0], pb1, 0);   GLB(BANK[1][1], pb1, 256);                  \
    GLB(BANK[1][2], pb1, 512); GLB(BANK[1][3], pb1, 768);                  \
    SB;                                                                    \
  }

#define MFMA16(BB, BANK)                                                   \
  {                                                                        \
    _Pragma("unroll")                                                      \
    for (int mt = 0; mt < 4; ++mt)                                         \
      _Pragma("unroll")                                                    \
      for (int nt = 0; nt < 4; ++nt)                                       \
        acc[mt][nt] = __builtin_amdgcn_mfma_f32_16x16x32_bf16(             \
            __builtin_bit_cast(bf16x8, Af[BB][mt]),                        \
            __builtin_bit_cast(bf16x8, BANK[BB][nt]),                      \
            acc[mt][nt], 0, 0, 0);                                         \
  }

  // one half-chunk: wait B bank, 8 ds_reads, 32 MFMAs (split for overlap)
#define HALF(N, BUF, A, BANK)                                              \
  {                                                                        \
    VMW(N);                                                                \
    DSR(Af[0][0], (BUF)*8448 + (A)*4224 + 0);                              \
    DSR(Af[0][1], (BUF)*8448 + (A)*4224 + 256);                            \
    DSR(Af[0][2], (BUF)*8448 + (A)*4224 + 512);                            \
    DSR(Af[0][3], (BUF)*8448 + (A)*4224 + 768);                            \
    DSR(Af[1][0], (BUF)*8448 + (A)*4224 + 16);                             \
    DSR(Af[1][1], (BUF)*8448 + (A)*4224 + 272);                            \
    DSR(Af[1][2], (BUF)*8448 + (A)*4224 + 528);                            \
    DSR(Af[1][3], (BUF)*8448 + (A)*4224 + 784);                            \
    LGK(4);                                                                \
    __builtin_amdgcn_s_setprio(1);                                         \
    MFMA16(0, BANK);                                                       \
    LGK(0);                                                                \
    MFMA16(1, BANK);                                                       \
    __builtin_amdgcn_s_setprio(0);                                         \
    SB;                                                                    \
  }

  SB;
  // ---- prologue: stage chunks 0,1; B banks for halves 0,1 ----
  STAGE(0, 0, tvA);
  STAGE(1, 1, tvB);
  ISSUEB(B0, 0, 0);                              // half 0 = (a0,c0)
  ISSUEB(B1, 1, 0);                              // half 1 = (a1,c0)
  VMW(19);                                       // stage(0) ready
  TAILW(0, tvA); LGK(0); BAR; SB;

  // ---- chunk 0 (buf 0) ----
  STAGE(2, 2, tvA);
  HALF(11, 0, 0, B0);  ISSUEB(B0, 0, 1);
  HALF(11, 0, 1, B1);  ISSUEB(B1, 1, 1);
  TAILW(1, tvB); LGK(0); BAR; SB;
  // ---- chunk 1 (buf 1) ----
  STAGE(0, 3, tvB);
  HALF(11, 1, 0, B0);  ISSUEB(B0, 0, 2);
  HALF(11, 1, 1, B1);  ISSUEB(B1, 1, 2);
  TAILW(2, tvA); LGK(0); BAR; SB;
  // ---- chunk 2 (buf 2) ----
  STAGE(1, 4, tvA);
  HALF(11, 2, 0, B0);  ISSUEB(B0, 0, 3);
  HALF(11, 2, 1, B1);  ISSUEB(B1, 1, 3);
  TAILW(0, tvB); LGK(0); BAR; SB;
  // ---- chunk 3 (buf 0) ----
  STAGE(2, 5, tvB);
  HALF(11, 0, 0, B0);  ISSUEB(B0, 0, 4);
  HALF(11, 0, 1, B1);  ISSUEB(B1, 1, 4);
  TAILW(1, tvA); LGK(0); BAR; SB;
  // ---- chunk 4 (buf 1) ----
  STAGE(0, 6, tvA);
  HALF(11, 1, 0, B0);  ISSUEB(B0, 0, 5);
  HALF(11, 1, 1, B1);  ISSUEB(B1, 1, 5);
  TAILW(2, tvB); LGK(0); BAR; SB;
  // ---- chunk 5 (buf 2) ----
  STAGE(1, 7, tvB);
  HALF(11, 2, 0, B0);  ISSUEB(B0, 0, 6);
  HALF(11, 2, 1, B1);  ISSUEB(B1, 1, 6);
  TAILW(0, tvA); LGK(0); BAR; SB;
  // ---- chunk 6 (buf 0) — no further staging ----
  HALF(8, 0, 0, B0);   ISSUEB(B0, 0, 7);
  HALF(8, 0, 1, B1);   ISSUEB(B1, 1, 7);
  TAILW(1, tvB); LGK(0); BAR; SB;
  // ---- chunk 7 (buf 1) ----
  HALF(8, 1, 0, B0);
  HALF(0, 1, 1, B1);

#undef SB
#undef BAR
#undef VMW
#undef LGK
#undef GLB
#undef DSR
#undef STAGE
#undef TAILW
#undef ISSUEB
#undef MFMA16
#undef HALF

  // ---------------- epilogue ----------------
  float scale = powf(sqrtf(128.f) / log1pf(128.f), alpha[0]);
  int oy = 2*u + py;
  float kq[4], bi[4];
  #pragma unroll
  for (int nt = 0; nt < 4; ++nt) {
    int n = coh*64 + nt*16 + l15;
    kq[nt] = ksq[n]; bi[nt] = bias[n];
  }
  size_t orow = ((size_t)b*128 + oy) * 128 * COUT;
  #pragma unroll
  for (int mt = 0; mt < 4; ++mt) {
    #pragma unroll
    for (int r = 0; r < 4; ++r) {
      int v = mt*16 + l4*4 + r;
      float ps = srow[v+px] + srow[v+px+1] + srow[66 + v+px] + srow[66 + v+px+1];
      #pragma unroll
      for (int nt = 0; nt < 4; ++nt) {
        float dot = acc[mt][nt][r];
        float dist = ps + kq[nt] - 2.f*dot + 1e-5f;
        float y = (dot*dot/dist + bi[nt]) * scale;
        int n = coh*64 + nt*16 + l15;
        out[orow + (size_t)(2*v + px)*COUT + n] = y;
      }
    }
  }
}

// ---------------- fallback (tiny ws): direct fp32 ----------------
__global__ __launch_bounds__(256) void fb_main(
    const float* __restrict__ x, const float* __restrict__ w,
    const float* __restrict__ bias, const float* __restrict__ alpha,
    const float* __restrict__ ksq, float* __restrict__ out)
{
  size_t idx = (size_t)blockIdx.x * 256 + threadIdx.x;
  int co = (int)(idx & 127);
  int ox = (int)((idx >> 7) & 127);
  int oy = (int)((idx >> 14) & 127);
  int b  = (int)(idx >> 21);
  int py = oy & 1, px = ox & 1, u = oy >> 1, v = ox >> 1;
  float dot = 0.f, ps = 0.f;
  for (int a = 0; a < 2; ++a) {
    int iy = u + py + a - 1;
    if (iy < 0 || iy > 63) continue;
    for (int b2 = 0; b2 < 2; ++b2) {
      int ix = v + px + b2 - 1;
      if (ix < 0 || ix > 63) continue;
      const float* xp = x + (((size_t)b*64 + iy)*64 + ix)*CIN;
      const float* wp = w + ((size_t)((py + 2*a)*4 + (px + 2*b2))*CIN)*COUT + co;
      for (int ci = 0; ci < CIN; ++ci) {
        float xv = xp[ci];
        dot += xv * wp[(size_t)ci*COUT];
        ps  += xv * xv;
      }
    }
  }
  float dist = ps + ksq[co] - 2.f*dot + 1e-5f;
  float scale = powf(sqrtf(128.f) / log1pf(128.f), alpha[0]);
  out[idx] = (dot*dot/dist + bias[co]) * scale;
}

// ---------------- launcher ----------------
extern "C" void kernel_launch(void* const* d_in, const int* in_sizes, int n_in,
                              void* d_out, int out_size, void* d_ws, size_t ws_size,
                              hipStream_t stream)
{
  const float* x     = (const float*)d_in[0];
  const float* w     = (const float*)d_in[1];
  const float* bias  = (const float*)d_in[2];
  const float* alpha = (const float*)d_in[3];
  float* out = (float*)d_out;

  if (ws_size < WS_NEEDED) {
    float* ksq = (float*)d_ws;
    fb_ksq<<<128, 256, 0, stream>>>(w, ksq);
    fb_main<<<131072, 256, 0, stream>>>(x, w, bias, alpha, ksq, out);
    return;
  }

  unsigned short* xpad = (unsigned short*)d_ws;
  unsigned short* wfp  = (unsigned short*)((char*)d_ws + WF_OFF);
  float* spad = (float*)((char*)d_ws + SPAD_OFF);
  float* ksq  = (float*)((char*)d_ws + KSQ_OFF);

  fb_ksq<<<128, 256, 0, stream>>>(w, ksq);
  prep_x<<<17424, 256, 0, stream>>>(x, xpad, spad);
  prep_w2<<<128, 256, 0, stream>>>(w, wfp);
  yat_main<<<2048, 256, 0, stream>>>(xpad, wfp, spad, ksq, bias, alpha, out);
}

// Round 12
// 112.987 us; speedup vs baseline: 1.0756x; 1.0074x over previous
//
#include <hip/hip_runtime.h>
#include <cstdint>
#include <cstddef>

#define CIN   256
#define COUT  128

typedef float  f32x4  __attribute__((ext_vector_type(4)));
typedef __bf16 bf16x8 __attribute__((ext_vector_type(8)));
typedef unsigned int u32x4 __attribute__((ext_vector_type(4)));

// ---------------- workspace layout (bytes) ----------------
// xpad: pixel-major padded x: [b][row 66][col 66][ci 256] bf16
#define XPAD_BYTES (16ull*66*66*256*2)          // 35,684,352
#define WF_OFF     XPAD_BYTES
#define WF_BYTES   (16ull*8*4*128*8*2)          // 1,048,576  bf16 w, frag-ordered
#define SPAD_OFF   (WF_OFF + WF_BYTES)
#define SPAD_BYTES (16ull*66*66*4)              // 278,784    fp32 per-pixel sum(x^2)
#define KSQ_OFF    (SPAD_OFF + SPAD_BYTES)
#define WS_NEEDED  (KSQ_OFF + 512)

__device__ __forceinline__ unsigned short f2bf(float f) {
  unsigned int u = __float_as_uint(f);
  u += 0x7fffu + ((u >> 16) & 1u);              // RNE
  return (unsigned short)(u >> 16);
}

__device__ __forceinline__ void async16(const void* lds, const void* g) {
  __builtin_amdgcn_global_load_lds(
      (const __attribute__((address_space(1))) unsigned int*)g,
      (__attribute__((address_space(3))) unsigned int*)lds, 16, 0, 0);
}

// ---------------- prep: pad+convert x, channel sum of x^2 ----------------
__global__ __launch_bounds__(256) void prep_x(
    const float* __restrict__ x, unsigned short* __restrict__ xpad,
    float* __restrict__ spad)
{
  int wave = threadIdx.x >> 6, lane = threadIdx.x & 63;
  int p = blockIdx.x * 4 + wave;                 // 0..69695 over [16][66][66]
  int b = p / 4356;
  int rem = p - b * 4356;
  int iyp = rem / 66, ixp = rem - iyp * 66;
  bool interior = (iyp >= 1 && iyp <= 64 && ixp >= 1 && ixp <= 64);
  f32x4 v = {0.f, 0.f, 0.f, 0.f};
  if (interior) {
    const float* src = x + (((size_t)b*64 + (iyp-1))*64 + (ixp-1))*CIN + lane*4;
    v = *(const f32x4*)src;
  }
  ushort4 h;
  h.x = f2bf(v.x); h.y = f2bf(v.y); h.z = f2bf(v.z); h.w = f2bf(v.w);
  *(ushort4*)(xpad + (size_t)p*CIN + lane*4) = h;
  float s = v.x*v.x + v.y*v.y + v.z*v.z + v.w*v.w;
  #pragma unroll
  for (int off = 32; off > 0; off >>= 1) s += __shfl_down(s, off);
  if (lane == 0) spad[p] = s;
}

// ---------------- prep: fragment-ordered weights ----------------
// wf element index: (((tap*8 + c8)*4 + q)*128 + co)*8 + e, ci = c8*32 + q*8 + e
__global__ __launch_bounds__(256) void prep_w2(
    const float* __restrict__ w, unsigned short* __restrict__ wf)
{
  int blk = blockIdx.x;                          // tap*8 + c8
  int tap = blk >> 3, c8 = blk & 7;
  int t = threadIdx.x;
  #pragma unroll
  for (int rr = 0; rr < 2; ++rr) {
    int row = rr*256 + t;                        // 0..511 = q*128 + co
    int q = row >> 7, co = row & 127;
    union { unsigned short u[8]; uint4 v; } hh;
    #pragma unroll
    for (int e = 0; e < 8; ++e) {
      int ci = c8*32 + q*8 + e;
      hh.u[e] = f2bf(w[((size_t)tap*256 + ci)*COUT + co]);
    }
    *(uint4*)(wf + ((size_t)blk*4 + q)*128*8 + (size_t)co*8) = hh.v;
  }
}

// ---------------- ksq: per-cout kernel squared norm ----------------
__global__ __launch_bounds__(256) void fb_ksq(const float* __restrict__ w,
                                              float* __restrict__ ksq) {
  __shared__ float red[256];
  int co = blockIdx.x, t = threadIdx.x;
  float s = 0.f;
  for (int j = t; j < 4096; j += 256) { float v = w[(size_t)j*COUT + co]; s += v*v; }
  red[t] = s; __syncthreads();
  for (int off = 128; off > 0; off >>= 1) {
    if (t < off) red[t] += red[t + off];
    __syncthreads();
  }
  if (t == 0) ksq[co] = red[0];
}

// ---------------- main fused kernel ----------------
// grid = 1024 (XCD-swizzled): bid -> b = bid>>6, u2 = (bid>>1)&31, py = bid&1
// block = 512 (8 waves): wave = px*4 + coq; per-wave tile 64 v x 32 co,
// TWO output rows (u = 2*u2 + j) sharing each B bank (2x intensity, B L2
// traffic halved vs R10). A: depth-3 LDS staging; B: depth-2 reg banks.
// Counted FIFO identical discipline to R10 (verified); bounds (512,2):
// 256-VGPR cap >> ~150 demand -> no spill (R11's crash was (512,8)'s 64-cap).
__global__ __launch_bounds__(512, 2) void yat_main(
    const unsigned short* __restrict__ xpad,
    const unsigned short* __restrict__ wf,
    const float* __restrict__ spad,
    const float* __restrict__ ksq,
    const float* __restrict__ bias,
    const float* __restrict__ alpha,
    float* __restrict__ out)
{
  __shared__ __align__(16) unsigned short xs[3][6336];   // 3 x 12672 B (792 segs)
  __shared__ float srow[198];

  int orig = blockIdx.x;
  int bid = (orig & 7) * 128 + (orig >> 3);              // XCD-contiguous (1024%8==0)
  int py = bid & 1, u2 = (bid >> 1) & 31, b = bid >> 6;
  int t = threadIdx.x, wave = t >> 6, lane = t & 63;
  int px = wave >> 2, coq = wave & 3;
  int l15 = lane & 15, l4 = lane >> 4;
  int base = 2*u2 + py;                                  // first A row

  if (t < 198) {
    int r = t / 66, c = t - r*66;
    srow[t] = spad[((size_t)b*66 + base + r)*66 + c];
  }

  const size_t xbase = ((size_t)b*66 + base) * 66 * CIN; // shorts

  // staging source offsets (shorts); seg s: row=s/264, q=(s%264)/66, col=s%66
  size_t soff0, soff1, stail;
  {
    int s = t;                                   // round 0: segs 0..511
    int row = s / 264; int r2 = s - row*264;
    int q = r2 / 66;  int c = r2 - q*66;
    soff0 = xbase + (size_t)(row*66 + c)*CIN + q*8;
    s = 512 + (t & 255);                         // round 1: segs 512..767 (dup'd)
    row = s / 264; r2 = s - row*264;
    q = r2 / 66;  c = r2 - q*66;
    soff1 = xbase + (size_t)(row*66 + c)*CIN + q*8;
    int ts = t & 31; if (ts > 23) ts = 23;       // tail segs 768..791 (uniform)
    s = 768 + ts;
    row = s / 264; r2 = s - row*264;
    q = r2 / 66;  c = r2 - q*66;
    stail = xbase + (size_t)(row*66 + c)*CIN + q*8;
  }

  // LDS byte address of this lane's A-frag base
  unsigned ab_lds = (unsigned)(unsigned long long)(&xs[0][0])
                    + (unsigned)((l4*66 + l15 + px) * 16);
  // B per-lane base: wf[tap py*4+px][q=l4][co = coq*32 + l15]
  const unsigned short* wb =
      wf + ((size_t)l4*128 + coq*32 + l15)*8 + (size_t)(py*4 + px)*32768;

  f32x4 acc[2][4][2];                                    // [j][mt][nt]
  #pragma unroll
  for (int j = 0; j < 2; ++j)
    #pragma unroll
    for (int i = 0; i < 4; ++i)
      #pragma unroll
      for (int n = 0; n < 2; ++n)
        acc[j][i][n] = (f32x4){0.f, 0.f, 0.f, 0.f};

  u32x4 B0[2][2], B1[2][2];                      // [bb][nt] banks (a=0 / a=1)
  u32x4 Af[2][4];                                // [bb][mt] current j's A frags
  u32x4 tvA, tvB;                                // staged tail values

#define SB  __builtin_amdgcn_sched_barrier(0)
#define BAR __builtin_amdgcn_s_barrier()
#define VMW(N) do { asm volatile("s_waitcnt vmcnt(" #N ")" ::: "memory"); SB; } while (0)
#define LGK(N) do { asm volatile("s_waitcnt lgkmcnt(" #N ")" ::: "memory"); SB; } while (0)

#define GLB(dst, base, off)                                                \
  asm volatile("global_load_dwordx4 %0, %1, off offset:%c2"                \
               : "=v"(dst) : "v"(base), "i"(off))

#define DSR(dst, off)                                                      \
  asm volatile("ds_read_b128 %0, %1 offset:%c2"                            \
               : "=v"(dst) : "v"(ab_lds), "i"(off))

  // stage chunk K into buffer BUF: 2 async16 rounds + tail GLB (3 vmem/wave)
#define STAGE(BUF, K, TV)                                                  \
  {                                                                        \
    async16(&xs[BUF][(size_t)(wave*64)*8],            xpad + soff0 + (K)*32); \
    async16(&xs[BUF][(size_t)(512 + (wave&3)*64)*8],  xpad + soff1 + (K)*32); \
    SB;                                                                    \
    GLB(TV, (const char*)(xpad + stail + (K)*32), 0);                      \
    SB;                                                                    \
  }

#define TAILW(BUF, TV)                                                     \
  { if (t < 24) *((u32x4*)&xs[BUF][(size_t)(768 + t)*8]) = TV; }

  // B bank: 4 loads. offsets: AA*524288 + bb*131072 + C8*8192 + nt*256
#define ISSUEB(BANK, AA, C8)                                               \
  {                                                                        \
    const char* pb0 = (const char*)wb + (AA)*524288 + (C8)*8192;           \
    const char* pb1 = pb0 + 131072;                                        \
    GLB(BANK[0][0], pb0, 0); GLB(BANK[0][1], pb0, 256);                    \
    GLB(BANK[1][0], pb1, 0); GLB(BANK[1][1], pb1, 256);                    \
    SB;                                                                    \
  }

#define DSRA(J, A, BUF)                                                    \
    DSR(Af[0][0], (BUF)*12672 + ((J)+(A))*4224 + 0);                       \
    DSR(Af[0][1], (BUF)*12672 + ((J)+(A))*4224 + 256);                     \
    DSR(Af[0][2], (BUF)*12672 + ((J)+(A))*4224 + 512);                     \
    DSR(Af[0][3], (BUF)*12672 + ((J)+(A))*4224 + 768);                     \
    DSR(Af[1][0], (BUF)*12672 + ((J)+(A))*4224 + 16);                      \
    DSR(Af[1][1], (BUF)*12672 + ((J)+(A))*4224 + 272);                     \
    DSR(Af[1][2], (BUF)*12672 + ((J)+(A))*4224 + 528);                     \
    DSR(Af[1][3], (BUF)*12672 + ((J)+(A))*4224 + 784);

#define MFMA8(J, BB, BANK)                                                 \
  {                                                                        \
    _Pragma("unroll")                                                      \
    for (int mt = 0; mt < 4; ++mt)                                         \
      _Pragma("unroll")                                                    \
      for (int nt = 0; nt < 2; ++nt)                                       \
        acc[J][mt][nt] = __builtin_amdgcn_mfma_f32_16x16x32_bf16(          \
            __builtin_bit_cast(bf16x8, Af[BB][mt]),                        \
            __builtin_bit_cast(bf16x8, BANK[BB][nt]),                      \
            acc[J][mt][nt], 0, 0, 0);                                      \
  }

  // half-chunk (tap row a): both output rows j=0,1 reuse BANK
#define HALF(N, BUF, A, BANK)                                              \
  {                                                                        \
    VMW(N);                                                                \
    DSRA(0, A, BUF); LGK(4);                                               \
    __builtin_amdgcn_s_setprio(1); MFMA8(0, 0, BANK); LGK(0);              \
    MFMA8(0, 1, BANK); __builtin_amdgcn_s_setprio(0);                      \
    DSRA(1, A, BUF); LGK(4);                                               \
    __builtin_amdgcn_s_setprio(1); MFMA8(1, 0, BANK); LGK(0);              \
    MFMA8(1, 1, BANK); __builtin_amdgcn_s_setprio(0);                      \
    SB;                                                                    \
  }

  SB;
  // ---- prologue: stage chunks 0,1; B banks for chunk 0 ----
  STAGE(0, 0, tvA);
  STAGE(1, 1, tvB);
  ISSUEB(B0, 0, 0);
  ISSUEB(B1, 1, 0);
  VMW(11);                                       // stage(0)+tvA retired
  TAILW(0, tvA); LGK(0); BAR; SB;

  // ---- chunk 0 (buf 0) ----
  STAGE(2, 2, tvA);
  HALF(7, 0, 0, B0);  ISSUEB(B0, 0, 1);
  HALF(7, 0, 1, B1);  ISSUEB(B1, 1, 1);
  TAILW(1, tvB); LGK(0); BAR; SB;
  // ---- chunk 1 (buf 1) ----
  STAGE(0, 3, tvB);
  HALF(7, 1, 0, B0);  ISSUEB(B0, 0, 2);
  HALF(7, 1, 1, B1);  ISSUEB(B1, 1, 2);
  TAILW(2, tvA); LGK(0); BAR; SB;
  // ---- chunk 2 (buf 2) ----
  STAGE(1, 4, tvA);
  HALF(7, 2, 0, B0);  ISSUEB(B0, 0, 3);
  HALF(7, 2, 1, B1);  ISSUEB(B1, 1, 3);
  TAILW(0, tvB); LGK(0); BAR; SB;
  // ---- chunk 3 (buf 0) ----
  STAGE(2, 5, tvB);
  HALF(7, 0, 0, B0);  ISSUEB(B0, 0, 4);
  HALF(7, 0, 1, B1);  ISSUEB(B1, 1, 4);
  TAILW(1, tvA); LGK(0); BAR; SB;
  // ---- chunk 4 (buf 1) ----
  STAGE(0, 6, tvA);
  HALF(7, 1, 0, B0);  ISSUEB(B0, 0, 5);
  HALF(7, 1, 1, B1);  ISSUEB(B1, 1, 5);
  TAILW(2, tvB); LGK(0); BAR; SB;
  // ---- chunk 5 (buf 2) ----
  STAGE(1, 7, tvB);
  HALF(7, 2, 0, B0);  ISSUEB(B0, 0, 6);
  HALF(7, 2, 1, B1);  ISSUEB(B1, 1, 6);
  TAILW(0, tvA); LGK(0); BAR; SB;
  // ---- chunk 6 (buf 0) — no further staging ----
  HALF(4, 0, 0, B0);  ISSUEB(B0, 0, 7);
  HALF(4, 0, 1, B1);  ISSUEB(B1, 1, 7);
  TAILW(1, tvB); LGK(0); BAR; SB;
  // ---- chunk 7 (buf 1) ----
  HALF(4, 1, 0, B0);
  HALF(0, 1, 1, B1);

#undef SB
#undef BAR
#undef VMW
#undef LGK
#undef GLB
#undef DSR
#undef STAGE
#undef TAILW
#undef ISSUEB
#undef DSRA
#undef MFMA8
#undef HALF

  __syncthreads();                               // srow visibility for epilogue

  // ---------------- epilogue ----------------
  float scale = powf(sqrtf(128.f) / log1pf(128.f), alpha[0]);
  float kq[2], bi[2];
  #pragma unroll
  for (int nt = 0; nt < 2; ++nt) {
    int n = coq*32 + nt*16 + l15;
    kq[nt] = ksq[n]; bi[nt] = bias[n];
  }
  #pragma unroll
  for (int j = 0; j < 2; ++j) {
    int oy = 4*u2 + 2*j + py;
    size_t orow = ((size_t)b*128 + oy) * 128 * COUT;
    #pragma unroll
    for (int mt = 0; mt < 4; ++mt) {
      #pragma unroll
      for (int r = 0; r < 4; ++r) {
        int v = mt*16 + l4*4 + r;
        float ps = srow[j*66 + v+px] + srow[j*66 + v+px+1]
                 + srow[(j+1)*66 + v+px] + srow[(j+1)*66 + v+px+1];
        #pragma unroll
        for (int nt = 0; nt < 2; ++nt) {
          float dot = acc[j][mt][nt][r];
          float dist = ps + kq[nt] - 2.f*dot + 1e-5f;
          float y = (dot*dot/dist + bi[nt]) * scale;
          int n = coq*32 + nt*16 + l15;
          out[orow + (size_t)(2*v + px)*COUT + n] = y;
        }
      }
    }
  }
}

// ---------------- fallback (tiny ws): direct fp32 ----------------
__global__ __launch_bounds__(256) void fb_main(
    const float* __restrict__ x, const float* __restrict__ w,
    const float* __restrict__ bias, const float* __restrict__ alpha,
    const float* __restrict__ ksq, float* __restrict__ out)
{
  size_t idx = (size_t)blockIdx.x * 256 + threadIdx.x;
  int co = (int)(idx & 127);
  int ox = (int)((idx >> 7) & 127);
  int oy = (int)((idx >> 14) & 127);
  int b  = (int)(idx >> 21);
  int py = oy & 1, px = ox & 1, u = oy >> 1, v = ox >> 1;
  float dot = 0.f, ps = 0.f;
  for (int a = 0; a < 2; ++a) {
    int iy = u + py + a - 1;
    if (iy < 0 || iy > 63) continue;
    for (int b2 = 0; b2 < 2; ++b2) {
      int ix = v + px + b2 - 1;
      if (ix < 0 || ix > 63) continue;
      const float* xp = x + (((size_t)b*64 + iy)*64 + ix)*CIN;
      const float* wp = w + ((size_t)((py + 2*a)*4 + (px + 2*b2))*CIN)*COUT + co;
      for (int ci = 0; ci < CIN; ++ci) {
        float xv = xp[ci];
        dot += xv * wp[(size_t)ci*COUT];
        ps  += xv * xv;
      }
    }
  }
  float dist = ps + ksq[co] - 2.f*dot + 1e-5f;
  float scale = powf(sqrtf(128.f) / log1pf(128.f), alpha[0]);
  out[idx] = (dot*dot/dist + bias[co]) * scale;
}

// ---------------- launcher ----------------
extern "C" void kernel_launch(void* const* d_in, const int* in_sizes, int n_in,
                              void* d_out, int out_size, void* d_ws, size_t ws_size,
                              hipStream_t stream)
{
  const float* x     = (const float*)d_in[0];
  const float* w     = (const float*)d_in[1];
  const float* bias  = (const float*)d_in[2];
  const float* alpha = (const float*)d_in[3];
  float* out = (float*)d_out;

  if (ws_size < WS_NEEDED) {
    float* ksq = (float*)d_ws;
    fb_ksq<<<128, 256, 0, stream>>>(w, ksq);
    fb_main<<<131072, 256, 0, stream>>>(x, w, bias, alpha, ksq, out);
    return;
  }

  unsigned short* xpad = (unsigned short*)d_ws;
  unsigned short* wfp  = (unsigned short*)((char*)d_ws + WF_OFF);
  float* spad = (float*)((char*)d_ws + SPAD_OFF);
  float* ksq  = (float*)((char*)d_ws + KSQ_OFF);

  fb_ksq<<<128, 256, 0, stream>>>(w, ksq);
  prep_x<<<17424, 256, 0, stream>>>(x, xpad, spad);
  prep_w2<<<128, 256, 0, stream>>>(w, wfp);
  yat_main<<<1024, 512, 0, stream>>>(xpad, wfp, spad, ksq, bias, alpha, out);
}